// Round 13
// baseline (503.218 us; speedup 1.0000x reference)
//
#include <hip/hip_runtime.h>
#include <hip/hip_bf16.h>

typedef unsigned char u8;
typedef unsigned int u32;
typedef unsigned long long u64;
typedef int i32x4 __attribute__((ext_vector_type(4)));
typedef int i32x8 __attribute__((ext_vector_type(8)));
typedef float f32x16 __attribute__((ext_vector_type(16)));

#define HD 2880          // H == I == 2880
#define GUN 5760         // 2*I
#define NEXP 8
#define NTOK 1024
#define NASSIGN 4096     // T*K
#define MAXPAD 5120      // padded routed rows (40 tiles x 128)
#define MAXTILES 40
#define SROWS 90         // 2880/32
#define RB 1440          // packed fp4 row bytes (2880/2)
#define XSB 120          // activation scale row bytes: 15 phases x 8
// per-phase image pieces (BK = 192)
#define APART 13312      // A image: pay [kb(6)][row(128)][16B]=12288 + scl [row][8]=1024
#define BPAY 18432       // B payload [kb(6)][col(192)][16B]
#define BPART 19968      // B image: payload + scl [col][8]=1536

// ---------------- global -> LDS direct staging (16B per lane) ----------------
__device__ __forceinline__ void gll16(const void* g, void* l) {
  __builtin_amdgcn_global_load_lds(
      (const __attribute__((address_space(1))) u32*)g,
      (__attribute__((address_space(3))) u32*)l, 16, 0, 0);
}

// i32x4 -> i32x8 with UNDEF high half (fp4 MFMA reads only regs 0-3)
__device__ __forceinline__ i32x8 ext8(i32x4 v) {
  return __builtin_shufflevector(v, v, 0, 1, 2, 3, -1, -1, -1, -1);
}

// ---------------- exact mxfp4 code helper ----------------
__device__ __forceinline__ int quant_code(float v, float inv) {
  float x = v * inv;
  float a = fabsf(x);
  int n;
  if (x > 0.f)
    n = (a > 0.25f) + (a > 0.75f) + (a > 1.25f) + (a > 1.75f) +
        (a > 2.5f)  + (a > 3.5f)  + (a > 5.f);
  else
    n = (a >= 0.25f) + (a >= 0.75f) + (a >= 1.25f) + (a >= 1.75f) +
        (a >= 2.5f)  + (a >= 3.5f)  + (a >= 5.f);
  return x < 0.f ? (8 | n) : n;   // x==0 -> n==0 -> code 0
}

// ---------------- routing ----------------
__global__ __launch_bounds__(256)
void route_k(const int* __restrict__ ridx, const float* __restrict__ rw,
             int* __restrict__ tt_e, int* __restrict__ tt_row0, int* __restrict__ tt_rows,
             int* __restrict__ atok, int* __restrict__ tok2row) {
  __shared__ int cnt[NEXP], cur[NEXP], poff[NEXP];
  int tid = threadIdx.x;
  if (tid < NEXP) { cnt[tid] = 0; cur[tid] = 0; }
  __syncthreads();
  for (int a = tid; a < NASSIGN; a += 256) atomicAdd(&cnt[ridx[a]], 1);
  __syncthreads();
  if (tid == 0) {
    int off = 0, nt = 0;
    for (int e = 0; e < NEXP; ++e) {
      poff[e] = off;
      int cc = cnt[e];
      int ntl = (cc + 127) >> 7;
      for (int i = 0; i < ntl; ++i) {
        int rem = cc - i * 128;
        tt_e[nt] = e; tt_row0[nt] = off + i * 128; tt_rows[nt] = rem < 128 ? rem : 128;
        ++nt;
      }
      off += ntl * 128;
    }
    for (; nt < 64; ++nt) { tt_e[nt] = 0; tt_row0[nt] = 0; tt_rows[nt] = 0; }
  }
  __syncthreads();
  for (int r2 = tid; r2 < MAXPAD; r2 += 256) atok[r2] = 0;
  __syncthreads();
  for (int a = tid; a < NASSIGN; a += 256) {
    int e = ridx[a];
    int p = atomicAdd(&cur[e], 1);
    int r2 = poff[e] + p;
    atok[r2] = a >> 2;
    tok2row[a] = r2;
  }
}

// ---------------- bodies: activation quant + weight repack ----------------
__device__ __forceinline__ void quant_x_body(int t, int tid, const float* __restrict__ x,
                                             u8* __restrict__ xqp, u8* __restrict__ xs) {
  if (tid >= 360) return;       // 360*8 = 2880
  const float* xp = x + (long)t * HD + tid * 8;
  float4 v0 = *reinterpret_cast<const float4*>(xp);
  float4 v1 = *reinterpret_cast<const float4*>(xp + 4);
  float vv[8] = {v0.x, v0.y, v0.z, v0.w, v1.x, v1.y, v1.z, v1.w};
  float am = 0.f;
#pragma unroll
  for (int j = 0; j < 8; ++j) am = fmaxf(am, fabsf(vv[j]));
  am = fmaxf(am, __shfl_xor(am, 1));
  am = fmaxf(am, __shfl_xor(am, 2));
  u32 eb = (__float_as_uint(am) >> 23) & 255u;
  float inv = __uint_as_float((256u - eb) << 23);
  u32 w = 0;
#pragma unroll
  for (int j = 0; j < 8; ++j) {
    u32 c = (am > 0.f) ? (u32)quant_code(vv[j], inv) : 0u;
    w |= c << (4 * j);          // low nibble = even k
  }
  *reinterpret_cast<u32*>(xqp + (long)t * RB + tid * 4) = w;
  if ((tid & 3) == 0) {
    int kb = tid >> 2;          // 0..89
    int p = kb / 6, j = kb % 6;
    xs[(long)t * XSB + p * 8 + j] = (u8)(am > 0.f ? (eb - 2u) : 0u);
  }
}

__device__ __forceinline__ void repack_body(int idx, int tid, const int* __restrict__ codes,
                                            const int* __restrict__ scales,
                                            u8* __restrict__ wqT, int NTILE) {
  const int ND = NTILE * 192;
  const int tile = idx / 15;       // e*NTILE + nt
  const int p = idx % 15;
  const int nt = tile % NTILE;
  const int e = tile / NTILE;
  const int col = tid % 192;
  const int kb0 = tid / 192;
  const int f = nt * 192 + col;
  u8* base = wqT + ((long)tile * 15 + p) * BPART;
#pragma unroll
  for (int i = 0; i < 3; ++i) {
    int kb = kb0 + 2 * i;
    const int* src = codes + ((long)e * HD + (p * 6 + kb) * 32) * ND + f;
    u32 w[4] = {0, 0, 0, 0};
#pragma unroll
    for (int j = 0; j < 32; ++j) {
      u32 c = (u32)src[(long)j * ND] & 15u;
      w[j >> 3] |= c << ((j & 7) * 4);
    }
    *reinterpret_cast<uint4*>(base + (kb * 192 + col) * 16) =
        make_uint4(w[0], w[1], w[2], w[3]);
  }
  if (tid < 192) {
    u64 v = 0;
#pragma unroll
    for (int kb = 0; kb < 6; ++kb) {
      u32 s = (u32)(scales[((long)e * SROWS + p * 6 + kb) * ND + f] + 115) & 255u;
      v |= (u64)s << (kb * 8);
    }
    *reinterpret_cast<u64*>(base + BPAY + col * 8) = v;
  }
}

// prep1: quant_x (1024 blocks) + GU repack (3600 blocks)
__global__ __launch_bounds__(384)
void prep1_k(const float* __restrict__ x, u8* __restrict__ xqp, u8* __restrict__ xs,
             const int* __restrict__ guc, const int* __restrict__ gus,
             u8* __restrict__ wqgT) {
  const int b = blockIdx.x;
  const int tid = threadIdx.x;
  if (b < NTOK) quant_x_body(b, tid, x, xqp, xs);
  else repack_body(b - NTOK, tid, guc, gus, wqgT, 30);
}

// ---------------- A gather: routed rows -> per-phase image xqT[mt][p][APART] ----
__global__ __launch_bounds__(384)
void gathx_k(const u8* __restrict__ xqp, const u8* __restrict__ xs,
             const int* __restrict__ atok, u8* __restrict__ xqT) {
  const int mt = blockIdx.x;
  const int tid = threadIdx.x;
  __shared__ int toks[128];
  if (tid < 128) toks[tid] = atok[mt * 128 + tid];
  __syncthreads();
  u8* base = xqT + (long)mt * (15 * APART);
#pragma unroll
  for (int i = 0; i < 30; ++i) {
    int idx = tid + i * 384;          // 11520 payload chunks
    int p = idx / 768, rem = idx % 768;
    uint4 v = *reinterpret_cast<const uint4*>(xqp + (long)toks[rem & 127] * RB +
                                              p * 96 + (rem >> 7) * 16);
    *reinterpret_cast<uint4*>(base + (long)p * APART + rem * 16) = v;
  }
#pragma unroll
  for (int i = 0; i < 5; ++i) {
    int idx = tid + i * 384;          // 1920 scale u64s
    int p = idx >> 7, row = idx & 127;
    u64 v = *reinterpret_cast<const u64*>(xs + (long)toks[row] * XSB + p * 8);
    *reinterpret_cast<u64*>(base + (long)p * APART + 12288 + row * 8) = v;
  }
}

// ---------------- MX-fp4 MFMA GEMM body (r11 schedule + phase window) ----------
// BM=128, BN=192, BK=192. 384 thr = 6 waves (2m x 3n), wave tile 64x64,
// 12 MFMA/thread/phase. stage(p+1) issued BEFORE compute(p); one __syncthreads
// per phase. Phase window [p0, pend) supports K-split. Tail tiles (rows<=64):
// wm=1 waves skip compute (still stage + barrier).
template<bool IS_GU>
__device__ __forceinline__ void gemm_body(
    int mt, int nt, int p0, int pend, bool addBias,
    const u8* __restrict__ At, const u8* __restrict__ Bt,
    const float* __restrict__ bias,
    const int* __restrict__ tt_e, const int* __restrict__ tt_rows,
    u8* __restrict__ gqT, float* __restrict__ partial) {
  constexpr int NTILE = IS_GU ? 30 : 15;

  const int rows = tt_rows[mt];
  if (rows <= 0) return;
  const int e = tt_e[mt];
  const int tid = threadIdx.x;
  const int lane = tid & 63;
  const int wid = tid >> 6;
  const int wm = wid & 1;            // 2 m-waves, span 64
  const int wn = wid >> 1;           // 3 n-waves, span 64
  const int ml = lane & 31;
  const int kc = lane >> 5;

  __shared__ __align__(16) u8 Tiles[2][36864];

  const u8* Abase = At + (long)mt * (15 * APART);
  const u8* Bbase = Bt + (long)(e * NTILE + nt) * (15 * BPART);

  // 2080 chunks: threads 0..159 stage 6, rest 5
  const u8* csrc[6]; int cstep[6], cdst[6]; bool cval[6];
#pragma unroll
  for (int i = 0; i < 6; ++i) {
    int c = tid + i * 384;
    cval[i] = (c < 2080);
    if (c < 832)       { csrc[i] = Abase + c * 16;         cstep[i] = APART; }
    else if (c < 2080) { csrc[i] = Bbase + (c - 832) * 16; cstep[i] = BPART; }
    else               { csrc[i] = Abase;                  cstep[i] = 0; }
    cdst[i] = cval[i] ? c * 16 : 0;
  }

  auto stage = [&](int buf, int p) {
#pragma unroll
    for (int i = 0; i < 6; ++i)
      if (cval[i]) gll16(csrc[i] + (long)p * cstep[i], &Tiles[buf][cdst[i]]);
  };

  stage(0, p0);   // prologue

  f32x16 acc[2][2];
#pragma unroll
  for (int a_ = 0; a_ < 2; ++a_)
#pragma unroll
    for (int b_ = 0; b_ < 2; ++b_)
#pragma unroll
      for (int k_ = 0; k_ < 16; ++k_) acc[a_][b_][k_] = 0.f;

  const int row0l = wm * 64 + ml;
  const int col0l = wn * 64 + ml;
  const bool act = (wm == 0) || (rows > 64);   // tail-wave compute skip
  const int np = pend - p0;

  __syncthreads();   // tile p0 staged

  for (int pi = 0; pi < np; ++pi) {
    const int cur = pi & 1;
    if (pi + 1 < np) stage(cur ^ 1, p0 + pi + 1);   // in flight under compute
    if (act) {
      const u8* T = Tiles[cur];
      u64 As0 = *reinterpret_cast<const u64*>(&T[12288 + row0l * 8]);
      u64 As1 = *reinterpret_cast<const u64*>(&T[12288 + (row0l + 32) * 8]);
      u64 Bs0 = *reinterpret_cast<const u64*>(&T[31744 + col0l * 8]);
      u64 Bs1 = *reinterpret_cast<const u64*>(&T[31744 + (col0l + 32) * 8]);
#pragma unroll
      for (int t = 0; t < 3; ++t) {
        const int kb = t * 2 + kc;
        const int sh = kb * 8;
        i32x4 af0 = *reinterpret_cast<const i32x4*>(&T[(kb * 128 + row0l) * 16]);
        i32x4 af1 = *reinterpret_cast<const i32x4*>(&T[(kb * 128 + row0l + 32) * 16]);
        i32x4 bf0 = *reinterpret_cast<const i32x4*>(&T[13312 + (kb * 192 + col0l) * 16]);
        i32x4 bf1 = *reinterpret_cast<const i32x4*>(&T[13312 + (kb * 192 + col0l + 32) * 16]);
        int sa0 = (int)((As0 >> sh) & 255), sa1 = (int)((As1 >> sh) & 255);
        int sb0 = (int)((Bs0 >> sh) & 255), sb1 = (int)((Bs1 >> sh) & 255);
        __builtin_amdgcn_s_setprio(1);
        acc[0][0] = __builtin_amdgcn_mfma_scale_f32_32x32x64_f8f6f4(
            ext8(af0), ext8(bf0), acc[0][0], 4, 4, 0, sa0, 0, sb0);
        acc[0][1] = __builtin_amdgcn_mfma_scale_f32_32x32x64_f8f6f4(
            ext8(af0), ext8(bf1), acc[0][1], 4, 4, 0, sa0, 0, sb1);
        acc[1][0] = __builtin_amdgcn_mfma_scale_f32_32x32x64_f8f6f4(
            ext8(af1), ext8(bf0), acc[1][0], 4, 4, 0, sa1, 0, sb0);
        acc[1][1] = __builtin_amdgcn_mfma_scale_f32_32x32x64_f8f6f4(
            ext8(af1), ext8(bf1), acc[1][1], 4, 4, 0, sa1, 0, sb1);
        __builtin_amdgcn_s_setprio(0);
      }
    }
    __syncthreads();   // drain stage(next) + all reads of buf cur done
  }

  // ---- epilogues ----
  const int hlf = lane >> 5;
  if constexpr (IS_GU) {
    u8* Glds = &Tiles[0][0];             // 128 x 48 bytes
    const int pdn = nt >> 1;             // DN phase holding this block's 96 I-cols
    const int half = nt & 1;
    bool evenl = ((lane & 1) == 0);
#pragma unroll
    for (int mf = 0; mf < 2; ++mf) {
      float gated[2][16];
#pragma unroll
      for (int nf = 0; nf < 2; ++nf) {
        int fgc = nt * 192 + wn * 64 + nf * 32 + ml;
        float bown = bias[e * GUN + fgc];
#pragma unroll
        for (int rr = 0; rr < 16; ++rr) {
          float z = acc[mf][nf][rr] + bown;
          float zp = __shfl_xor(z, 1);
          float g = evenl ? z : zp;
          float u = evenl ? zp : z;
          g = fminf(g, 7.f);
          u = fminf(fmaxf(u, -7.f), 7.f);
          float sg = 1.f / (1.f + expf(-1.702f * g));
          gated[nf][rr] = (u + 1.f) * (g * sg);
        }
      }
#pragma unroll
      for (int rr = 0; rr < 16; ++rr) {
        float am = fmaxf(fabsf(gated[0][rr]), fabsf(gated[1][rr]));
        am = fmaxf(am, __shfl_xor(am, 2));
        am = fmaxf(am, __shfl_xor(am, 4));
        am = fmaxf(am, __shfl_xor(am, 8));
        am = fmaxf(am, __shfl_xor(am, 16));
        u32 eb = (__float_as_uint(am) >> 23) & 255u;
        float inv = __uint_as_float((256u - eb) << 23);
        int c0 = (am > 0.f) ? quant_code(gated[0][rr], inv) : 0;
        int c1 = (am > 0.f) ? quant_code(gated[1][rr], inv) : 0;
        int b0 = c0 | (__shfl_xor(c0, 2) << 4);   // valid at (lane&3)==0
        int b1 = c1 | (__shfl_xor(c1, 2) << 4);
        int mrow = (rr & 3) + 8 * (rr >> 2) + 4 * hlf;
        int rloc = wm * 64 + mf * 32 + mrow;
        if ((lane & 3) == 0) {
          Glds[rloc * 48 + wn * 16 + (ml >> 2)] = (u8)b0;
          Glds[rloc * 48 + wn * 16 + 8 + (ml >> 2)] = (u8)b1;
          if (rloc < rows && ml == 0)
            gqT[((long)mt * 15 + pdn) * APART + 12288 + rloc * 8 + half * 3 + wn] =
                (u8)(am > 0.f ? (eb - 2u) : 0u);
        }
      }
    }
    __syncthreads();
    {
      int part = tid >> 7, row = tid & 127;
      uint4 v = *reinterpret_cast<const uint4*>(&Glds[row * 48 + part * 16]);
      *reinterpret_cast<uint4*>(gqT + ((long)mt * 15 + pdn) * APART +
                                ((half * 3 + part) * 128 + row) * 16) = v;
    }
  } else {
    const int row0 = mt * 128;
#pragma unroll
    for (int mf = 0; mf < 2; ++mf) {
#pragma unroll
      for (int rr = 0; rr < 16; ++rr) {
        int mrow = (rr & 3) + 8 * (rr >> 2) + 4 * hlf;
        int rloc = wm * 64 + mf * 32 + mrow;
        if (rloc >= rows) continue;
        long rg = row0 + rloc;
#pragma unroll
        for (int nf = 0; nf < 2; ++nf) {
          int hg = nt * 192 + wn * 64 + nf * 32 + ml;
          float b = addBias ? bias[e * HD + hg] : 0.f;
          partial[rg * HD + hg] = acc[mf][nf][rr] + b;
        }
      }
    }
  }
}

// fused: GU GEMM (1200 blocks) + DN weight repack (1800 blocks) in one dispatch
__global__ __launch_bounds__(384, 3)
void gu_fused_k(const u8* __restrict__ xqT, const u8* __restrict__ wqgT,
                const float* __restrict__ gub,
                const int* __restrict__ tt_e, const int* __restrict__ tt_rows,
                u8* __restrict__ gqT,
                const int* __restrict__ dnc, const int* __restrict__ dns,
                u8* __restrict__ wqdT) {
  if (blockIdx.x < 1200) {
    // XCD-chunked bijective swizzle over 1200 GEMM blocks, mt fastest
    int lin = blockIdx.x;
    int xcd = lin & 7, pos = lin >> 3;
    int L = xcd * 150 + pos;
    gemm_body<true>(L % 40, L / 40, 0, 15, true,
                    xqT, wqgT, gub, tt_e, tt_rows, gqT, nullptr);
  } else {
    repack_body(blockIdx.x - 1200, threadIdx.x, dnc, dns, wqdT, 15);
  }
}

// DN GEMM, K-split 2x: 1200 blocks = 40 mt x 15 nt x 2 kh
__global__ __launch_bounds__(384, 3)
void dn_k(const u8* __restrict__ gqT, const u8* __restrict__ wqdT,
          const float* __restrict__ dnb,
          const int* __restrict__ tt_e, const int* __restrict__ tt_rows,
          float* __restrict__ partial) {
  int lin = blockIdx.x;
  int xcd = lin & 7, pos = lin >> 3;
  int L = xcd * 150 + pos;
  int mt = L % 40;
  int rest = L / 40;               // 0..29
  int nt = rest % 15;
  int kh = rest / 15;              // 0 or 1
  float* pdst = partial + (long)kh * MAXPAD * HD;
  if (kh == 0)
    gemm_body<false>(mt, nt, 0, 8, true, gqT, wqdT, dnb, tt_e, tt_rows, nullptr, pdst);
  else
    gemm_body<false>(mt, nt, 8, 15, false, gqT, wqdT, dnb, tt_e, tt_rows, nullptr, pdst);
}

// ---------------- final combine: out[t] = sum_k rw[t,k] * (p0+p1)[row(t,k)] ----
__global__ __launch_bounds__(768)
void gather_k(const float* __restrict__ partial, const int* __restrict__ tok2row,
              const float* __restrict__ rw, float* __restrict__ out) {
  int t = blockIdx.x;
  int i = threadIdx.x;
  if (i >= 720) return;            // 720*4 = 2880
  int c = i * 4;
  const float* p2 = partial + (long)MAXPAD * HD;
  float4 s = make_float4(0.f, 0.f, 0.f, 0.f);
#pragma unroll
  for (int k = 0; k < 4; ++k) {
    int r = tok2row[t * 4 + k];
    float w = rw[t * 4 + k];
    float4 v = *reinterpret_cast<const float4*>(&partial[(long)r * HD + c]);
    float4 v2 = *reinterpret_cast<const float4*>(&p2[(long)r * HD + c]);
    s.x += w * (v.x + v2.x); s.y += w * (v.y + v2.y);
    s.z += w * (v.z + v2.z); s.w += w * (v.w + v2.w);
  }
  *reinterpret_cast<float4*>(&out[(long)t * HD + c]) = s;
}

// ---------------- launcher ----------------
extern "C" void kernel_launch(void* const* d_in, const int* in_sizes, int n_in,
                              void* d_out, int out_size, void* d_ws, size_t ws_size,
                              hipStream_t stream) {
  (void)in_sizes; (void)n_in; (void)ws_size; (void)out_size;
  const float* x   = (const float*)d_in[0];
  const int* ridx  = (const int*)d_in[1];
  const float* rw  = (const float*)d_in[2];
  const int* guc   = (const int*)d_in[3];
  const int* gus   = (const int*)d_in[4];
  const float* gub = (const float*)d_in[5];
  const int* dnc   = (const int*)d_in[6];
  const int* dns   = (const int*)d_in[7];
  const float* dnb = (const float*)d_in[8];
  float* out = (float*)d_out;
  char* ws = (char*)d_ws;

  // ws layout (~244 MB)
  int* tt_e    = (int*)(ws);
  int* tt_row0 = (int*)(ws + 1024);
  int* tt_rows = (int*)(ws + 2048);
  int* atok    = (int*)(ws + 4096);
  int* tok2row = (int*)(ws + 4096 + MAXPAD * 4);
  size_t off = 65536;
  u8* xqp = (u8*)(ws + off);  off += (size_t)NTOK * RB;               // 1.47 MB
  u8* xs  = (u8*)(ws + off);  off += (size_t)NTOK * XSB;              // 123 KB
  u8* xqT = (u8*)(ws + off);  off += (size_t)MAXTILES * 15 * APART;   // 7.99 MB
  u8* gqT = (u8*)(ws + off);  off += (size_t)MAXTILES * 15 * APART;   // 7.99 MB
  u8* wqgT = (u8*)(ws + off); off += (size_t)NEXP * 30 * 15 * BPART;  // 71.9 MB
  u8* wqdT = (u8*)(ws + off); off += (size_t)NEXP * 15 * 15 * BPART;  // 35.9 MB
  float* partial = (float*)(ws + off); off += 2 * (size_t)MAXPAD * HD * 4; // 118 MB

  route_k<<<1, 256, 0, stream>>>(ridx, rw, tt_e, tt_row0, tt_rows, atok, tok2row);
  prep1_k<<<NTOK + 3600, 384, 0, stream>>>(x, xqp, xs, guc, gus, wqgT);
  gathx_k<<<MAXTILES, 384, 0, stream>>>(xqp, xs, atok, xqT);
  gu_fused_k<<<1200 + 1800, 384, 0, stream>>>(xqT, wqgT, gub, tt_e, tt_rows, gqT,
                                              dnc, dns, wqdT);
  dn_k<<<1200, 384, 0, stream>>>(gqT, wqdT, dnb, tt_e, tt_rows, partial);
  gather_k<<<NTOK, 768, 0, stream>>>(partial, tok2row, rw, out);
}

// Round 15
// 384.005 us; speedup vs baseline: 1.3104x; 1.3104x over previous
//
#include <hip/hip_runtime.h>
#include <hip/hip_bf16.h>

typedef unsigned char u8;
typedef unsigned int u32;
typedef unsigned long long u64;
typedef int i32x4 __attribute__((ext_vector_type(4)));
typedef int i32x8 __attribute__((ext_vector_type(8)));
typedef float f32x16 __attribute__((ext_vector_type(16)));

#define HD 2880          // H == I == 2880
#define GUN 5760         // 2*I
#define NEXP 8
#define NTOK 1024
#define NASSIGN 4096     // T*K
#define MAXPAD 5120      // padded routed rows (40 tiles x 128)
#define MAXTILES 40
#define SROWS 90         // 2880/32
#define RB 1440          // packed fp4 row bytes (2880/2)
#define XSB 120          // activation scale row bytes: 15 phases x 8
// per-phase image pieces (BK = 192)
#define APART 13312      // A image: pay [kb(6)][row(128)][16B]=12288 + scl [row][8]=1024
#define BPGU 13312       // GU B image: pay [kb(6)][col(128)][16B]=12288 + scl [col][8]=1024
#define BPAY 18432       // DN B payload [kb(6)][col(192)][16B]
#define BPART 19968      // DN B image: payload + scl [col][8]=1536

// ---------------- global -> LDS direct staging (16B per lane) ----------------
__device__ __forceinline__ void gll16(const void* g, void* l) {
  __builtin_amdgcn_global_load_lds(
      (const __attribute__((address_space(1))) u32*)g,
      (__attribute__((address_space(3))) u32*)l, 16, 0, 0);
}

// i32x4 -> i32x8 with UNDEF high half (fp4 MFMA reads only regs 0-3)
__device__ __forceinline__ i32x8 ext8(i32x4 v) {
  return __builtin_shufflevector(v, v, 0, 1, 2, 3, -1, -1, -1, -1);
}

// ---------------- exact mxfp4 code helper ----------------
__device__ __forceinline__ int quant_code(float v, float inv) {
  float x = v * inv;
  float a = fabsf(x);
  int n;
  if (x > 0.f)
    n = (a > 0.25f) + (a > 0.75f) + (a > 1.25f) + (a > 1.75f) +
        (a > 2.5f)  + (a > 3.5f)  + (a > 5.f);
  else
    n = (a >= 0.25f) + (a >= 0.75f) + (a >= 1.25f) + (a >= 1.75f) +
        (a >= 2.5f)  + (a >= 3.5f)  + (a >= 5.f);
  return x < 0.f ? (8 | n) : n;   // x==0 -> n==0 -> code 0
}

// ---------------- routing ----------------
__global__ __launch_bounds__(256)
void route_k(const int* __restrict__ ridx, const float* __restrict__ rw,
             int* __restrict__ tt_e, int* __restrict__ tt_row0, int* __restrict__ tt_rows,
             int* __restrict__ atok, int* __restrict__ tok2row) {
  __shared__ int cnt[NEXP], cur[NEXP], poff[NEXP];
  int tid = threadIdx.x;
  if (tid < NEXP) { cnt[tid] = 0; cur[tid] = 0; }
  __syncthreads();
  for (int a = tid; a < NASSIGN; a += 256) atomicAdd(&cnt[ridx[a]], 1);
  __syncthreads();
  if (tid == 0) {
    int off = 0, nt = 0;
    for (int e = 0; e < NEXP; ++e) {
      poff[e] = off;
      int cc = cnt[e];
      int ntl = (cc + 127) >> 7;
      for (int i = 0; i < ntl; ++i) {
        int rem = cc - i * 128;
        tt_e[nt] = e; tt_row0[nt] = off + i * 128; tt_rows[nt] = rem < 128 ? rem : 128;
        ++nt;
      }
      off += ntl * 128;
    }
    for (; nt < 64; ++nt) { tt_e[nt] = 0; tt_row0[nt] = 0; tt_rows[nt] = 0; }
  }
  __syncthreads();
  for (int r2 = tid; r2 < MAXPAD; r2 += 256) atok[r2] = 0;
  __syncthreads();
  for (int a = tid; a < NASSIGN; a += 256) {
    int e = ridx[a];
    int p = atomicAdd(&cur[e], 1);
    int r2 = poff[e] + p;
    atok[r2] = a >> 2;
    tok2row[a] = r2;
  }
}

// ---------------- activation quant ----------------
__device__ __forceinline__ void quant_x_body(int t, int tid, const float* __restrict__ x,
                                             u8* __restrict__ xqp, u8* __restrict__ xs) {
  if (tid >= 360) return;       // 360*8 = 2880
  const float* xp = x + (long)t * HD + tid * 8;
  float4 v0 = *reinterpret_cast<const float4*>(xp);
  float4 v1 = *reinterpret_cast<const float4*>(xp + 4);
  float vv[8] = {v0.x, v0.y, v0.z, v0.w, v1.x, v1.y, v1.z, v1.w};
  float am = 0.f;
#pragma unroll
  for (int j = 0; j < 8; ++j) am = fmaxf(am, fabsf(vv[j]));
  am = fmaxf(am, __shfl_xor(am, 1));
  am = fmaxf(am, __shfl_xor(am, 2));
  u32 eb = (__float_as_uint(am) >> 23) & 255u;
  float inv = __uint_as_float((256u - eb) << 23);
  u32 w = 0;
#pragma unroll
  for (int j = 0; j < 8; ++j) {
    u32 c = (am > 0.f) ? (u32)quant_code(vv[j], inv) : 0u;
    w |= c << (4 * j);          // low nibble = even k
  }
  *reinterpret_cast<u32*>(xqp + (long)t * RB + tid * 4) = w;
  if ((tid & 3) == 0) {
    int kb = tid >> 2;          // 0..89
    int p = kb / 6, j = kb % 6;
    xs[(long)t * XSB + p * 8 + j] = (u8)(am > 0.f ? (eb - 2u) : 0u);
  }
}

// ---------------- GU weight repack -> wqgT[(e*45+nt)][p][BPGU], 384 thr ----------
__device__ __forceinline__ void repack_gu_body(int idx, int tid,
                                               const int* __restrict__ codes,
                                               const int* __restrict__ scales,
                                               u8* __restrict__ wqgT) {
  const int ND = GUN;
  const int tile = idx / 15;       // e*45 + nt
  const int p = idx % 15;
  const int nt = tile % 45;
  const int e = tile / 45;
  u8* base = wqgT + ((long)tile * 15 + p) * BPGU;
  // payload: 768 chunks [kb(6)][col(128)]
#pragma unroll
  for (int i = 0; i < 2; ++i) {
    int c = tid + i * 384;
    int col = c & 127, kb = c >> 7;
    const int f = nt * 128 + col;
    const int* src = codes + ((long)e * HD + (p * 6 + kb) * 32) * ND + f;
    u32 w[4] = {0, 0, 0, 0};
#pragma unroll
    for (int j = 0; j < 32; ++j) {
      u32 cc = (u32)src[(long)j * ND] & 15u;
      w[j >> 3] |= cc << ((j & 7) * 4);
    }
    *reinterpret_cast<uint4*>(base + c * 16) = make_uint4(w[0], w[1], w[2], w[3]);
  }
  if (tid < 128) {
    const int f = nt * 128 + tid;
    u64 v = 0;
#pragma unroll
    for (int kb = 0; kb < 6; ++kb) {
      u32 s = (u32)(scales[((long)e * SROWS + p * 6 + kb) * ND + f] + 115) & 255u;
      v |= (u64)s << (kb * 8);
    }
    *reinterpret_cast<u64*>(base + 12288 + tid * 8) = v;
  }
}

// prep1: quant_x (1024 blocks) + GU repack (5400 blocks), 384 thr
__global__ __launch_bounds__(384)
void prep1_k(const float* __restrict__ x, u8* __restrict__ xqp, u8* __restrict__ xs,
             const int* __restrict__ guc, const int* __restrict__ gus,
             u8* __restrict__ wqgT) {
  const int b = blockIdx.x;
  const int tid = threadIdx.x;
  if (b < NTOK) quant_x_body(b, tid, x, xqp, xs);
  else repack_gu_body(b - NTOK, tid, guc, gus, wqgT);
}

// ---------------- DN weight repack (r11 layout), 256-thread variant ----------
__device__ __forceinline__ void repack_dn_body(int idx, int tid,
                                               const int* __restrict__ codes,
                                               const int* __restrict__ scales,
                                               u8* __restrict__ wqdT) {
  const int ND = HD;
  const int tile = idx / 15;       // e*15 + nt
  const int p = idx % 15;
  const int nt = tile % 15;
  const int e = tile / 15;
  u8* base = wqdT + ((long)tile * 15 + p) * BPART;
  // payload: 1152 chunks [kb(6)][col(192)]
#pragma unroll
  for (int i = 0; i < 5; ++i) {
    int c = tid + i * 256;
    if (c < 1152) {
      int col = c % 192, kb = c / 192;
      const int f = nt * 192 + col;
      const int* src = codes + ((long)e * HD + (p * 6 + kb) * 32) * ND + f;
      u32 w[4] = {0, 0, 0, 0};
#pragma unroll
      for (int j = 0; j < 32; ++j) {
        u32 cc = (u32)src[(long)j * ND] & 15u;
        w[j >> 3] |= cc << ((j & 7) * 4);
      }
      *reinterpret_cast<uint4*>(base + c * 16) = make_uint4(w[0], w[1], w[2], w[3]);
    }
  }
  if (tid < 192) {
    const int f = nt * 192 + tid;
    u64 v = 0;
#pragma unroll
    for (int kb = 0; kb < 6; ++kb) {
      u32 s = (u32)(scales[((long)e * SROWS + p * 6 + kb) * ND + f] + 115) & 255u;
      v |= (u64)s << (kb * 8);
    }
    *reinterpret_cast<u64*>(base + BPAY + tid * 8) = v;
  }
}

// ---------------- A gather: routed rows -> per-phase image xqT[mt][p][APART] ----
__global__ __launch_bounds__(384)
void gathx_k(const u8* __restrict__ xqp, const u8* __restrict__ xs,
             const int* __restrict__ atok, u8* __restrict__ xqT) {
  const int mt = blockIdx.x;
  const int tid = threadIdx.x;
  __shared__ int toks[128];
  if (tid < 128) toks[tid] = atok[mt * 128 + tid];
  __syncthreads();
  u8* base = xqT + (long)mt * (15 * APART);
#pragma unroll
  for (int i = 0; i < 30; ++i) {
    int idx = tid + i * 384;          // 11520 payload chunks
    int p = idx / 768, rem = idx % 768;
    uint4 v = *reinterpret_cast<const uint4*>(xqp + (long)toks[rem & 127] * RB +
                                              p * 96 + (rem >> 7) * 16);
    *reinterpret_cast<uint4*>(base + (long)p * APART + rem * 16) = v;
  }
#pragma unroll
  for (int i = 0; i < 5; ++i) {
    int idx = tid + i * 384;          // 1920 scale u64s
    int p = idx >> 7, row = idx & 127;
    u64 v = *reinterpret_cast<const u64*>(xs + (long)toks[row] * XSB + p * 8);
    *reinterpret_cast<u64*>(base + (long)p * APART + 12288 + row * 8) = v;
  }
}

// ---------------- GU GEMM body: BN=128, 4 waves (2m x 2n), 3 blocks/CU --------
// BM=128, BK=192 -> 15 phases, 12 MFMA/thread/phase (unchanged inner mix).
// LDS 2 x 26624 = 53 KB -> 3 desynced blocks/CU (inter-block stage/MFMA overlap).
__device__ __forceinline__ void gu_gemm_body(
    int lin, const u8* __restrict__ xqT, const u8* __restrict__ wqgT,
    const float* __restrict__ gub,
    const int* __restrict__ tt_e, const int* __restrict__ tt_rows,
    u8* __restrict__ gqT) {
  // XCD-chunked bijective swizzle over 1800 blocks, mt fastest
  int xcd = lin & 7, pos = lin >> 3;
  int L = xcd * 225 + pos;
  int mt = L % 40, nt = L / 40;        // nt 0..44

  const int rows = tt_rows[mt];
  if (rows <= 0) return;
  const int e = tt_e[mt];
  const int tid = threadIdx.x;         // 0..255
  const int lane = tid & 63;
  const int wid = tid >> 6;            // 0..3
  const int wm = wid & 1;              // 2 m-waves, span 64
  const int wn = wid >> 1;             // 2 n-waves, span 64
  const int ml = lane & 31;
  const int kc = lane >> 5;

  __shared__ __align__(16) u8 Tiles[2][26624];

  const u8* Abase = xqT + (long)mt * (15 * APART);
  const u8* Bbase = wqgT + (long)(e * 45 + nt) * (15 * BPGU);

  // 1664 chunks: threads 0..127 stage 7, rest 6
  const u8* csrc[7]; int cstep[7], cdst[7]; bool cval[7];
#pragma unroll
  for (int i = 0; i < 7; ++i) {
    int c = tid + i * 256;
    cval[i] = (c < 1664);
    if (c < 832)       { csrc[i] = Abase + c * 16;         cstep[i] = APART; cdst[i] = c * 16; }
    else if (c < 1664) { csrc[i] = Bbase + (c - 832) * 16; cstep[i] = BPGU;  cdst[i] = 13312 + (c - 832) * 16; }
    else               { csrc[i] = Abase; cstep[i] = 0; cdst[i] = 0; }
  }
  auto stage = [&](int buf, int p) {
#pragma unroll
    for (int i = 0; i < 7; ++i)
      if (cval[i]) gll16(csrc[i] + (long)p * cstep[i], &Tiles[buf][cdst[i]]);
  };

  stage(0, 0);

  f32x16 acc[2][2];
#pragma unroll
  for (int a_ = 0; a_ < 2; ++a_)
#pragma unroll
    for (int b_ = 0; b_ < 2; ++b_)
#pragma unroll
      for (int k_ = 0; k_ < 16; ++k_) acc[a_][b_][k_] = 0.f;

  const int row0l = wm * 64 + ml;
  const int col0l = wn * 64 + ml;
  const bool act = (wm == 0) || (rows > 64);

  __syncthreads();   // tile 0 staged

  for (int p = 0; p < 15; ++p) {
    const int cur = p & 1;
    if (p + 1 < 15) stage(cur ^ 1, p + 1);   // in flight under compute
    if (act) {
      const u8* T = Tiles[cur];
      u64 As0 = *reinterpret_cast<const u64*>(&T[12288 + row0l * 8]);
      u64 As1 = *reinterpret_cast<const u64*>(&T[12288 + (row0l + 32) * 8]);
      u64 Bs0 = *reinterpret_cast<const u64*>(&T[25600 + col0l * 8]);
      u64 Bs1 = *reinterpret_cast<const u64*>(&T[25600 + (col0l + 32) * 8]);
#pragma unroll
      for (int t = 0; t < 3; ++t) {
        const int kb = t * 2 + kc;
        const int sh = kb * 8;
        i32x4 af0 = *reinterpret_cast<const i32x4*>(&T[(kb * 128 + row0l) * 16]);
        i32x4 af1 = *reinterpret_cast<const i32x4*>(&T[(kb * 128 + row0l + 32) * 16]);
        i32x4 bf0 = *reinterpret_cast<const i32x4*>(&T[13312 + (kb * 128 + col0l) * 16]);
        i32x4 bf1 = *reinterpret_cast<const i32x4*>(&T[13312 + (kb * 128 + col0l + 32) * 16]);
        int sa0 = (int)((As0 >> sh) & 255), sa1 = (int)((As1 >> sh) & 255);
        int sb0 = (int)((Bs0 >> sh) & 255), sb1 = (int)((Bs1 >> sh) & 255);
        __builtin_amdgcn_s_setprio(1);
        acc[0][0] = __builtin_amdgcn_mfma_scale_f32_32x32x64_f8f6f4(
            ext8(af0), ext8(bf0), acc[0][0], 4, 4, 0, sa0, 0, sb0);
        acc[0][1] = __builtin_amdgcn_mfma_scale_f32_32x32x64_f8f6f4(
            ext8(af0), ext8(bf1), acc[0][1], 4, 4, 0, sa0, 0, sb1);
        acc[1][0] = __builtin_amdgcn_mfma_scale_f32_32x32x64_f8f6f4(
            ext8(af1), ext8(bf0), acc[1][0], 4, 4, 0, sa1, 0, sb0);
        acc[1][1] = __builtin_amdgcn_mfma_scale_f32_32x32x64_f8f6f4(
            ext8(af1), ext8(bf1), acc[1][1], 4, 4, 0, sa1, 0, sb1);
        __builtin_amdgcn_s_setprio(0);
      }
    }
    __syncthreads();
  }

  // ---- GU epilogue: 64 I-cols/block -> scale blocks {2nt, 2nt+1} ----
  const int hlf = lane >> 5;
  u8* Glds = &Tiles[0][0];             // 128 rows x 32 bytes
  const int pdn = nt / 3;              // 2nt/6
  const int kb0 = 2 * (nt % 3);        // even: never straddles a DN phase
  bool evenl = ((lane & 1) == 0);
#pragma unroll
  for (int mf = 0; mf < 2; ++mf) {
    float gated[2][16];
#pragma unroll
    for (int nf = 0; nf < 2; ++nf) {
      int fgc = nt * 128 + wn * 64 + nf * 32 + ml;
      float bown = gub[e * GUN + fgc];
#pragma unroll
      for (int rr = 0; rr < 16; ++rr) {
        float z = acc[mf][nf][rr] + bown;
        float zp = __shfl_xor(z, 1);
        float g = evenl ? z : zp;
        float u = evenl ? zp : z;
        g = fminf(g, 7.f);
        u = fminf(fmaxf(u, -7.f), 7.f);
        float sg = 1.f / (1.f + expf(-1.702f * g));
        gated[nf][rr] = (u + 1.f) * (g * sg);
      }
    }
#pragma unroll
    for (int rr = 0; rr < 16; ++rr) {
      float am = fmaxf(fabsf(gated[0][rr]), fabsf(gated[1][rr]));
      am = fmaxf(am, __shfl_xor(am, 2));
      am = fmaxf(am, __shfl_xor(am, 4));
      am = fmaxf(am, __shfl_xor(am, 8));
      am = fmaxf(am, __shfl_xor(am, 16));
      u32 eb = (__float_as_uint(am) >> 23) & 255u;
      float inv = __uint_as_float((256u - eb) << 23);
      int c0 = (am > 0.f) ? quant_code(gated[0][rr], inv) : 0;
      int c1 = (am > 0.f) ? quant_code(gated[1][rr], inv) : 0;
      int b0 = c0 | (__shfl_xor(c0, 2) << 4);   // valid at (lane&3)==0
      int b1 = c1 | (__shfl_xor(c1, 2) << 4);
      int mrow = (rr & 3) + 8 * (rr >> 2) + 4 * hlf;
      int rloc = wm * 64 + mf * 32 + mrow;
      if ((lane & 3) == 0) {
        Glds[rloc * 32 + wn * 16 + (ml >> 2)] = (u8)b0;
        Glds[rloc * 32 + wn * 16 + 8 + (ml >> 2)] = (u8)b1;
        if (rloc < rows && ml == 0)
          gqT[((long)mt * 15 + pdn) * APART + 12288 + rloc * 8 + kb0 + wn] =
              (u8)(am > 0.f ? (eb - 2u) : 0u);
      }
    }
  }
  __syncthreads();
  {
    int part = tid >> 7, row = tid & 127;     // 2 chunks x 128 rows
    uint4 v = *reinterpret_cast<const uint4*>(&Glds[row * 32 + part * 16]);
    *reinterpret_cast<uint4*>(gqT + ((long)mt * 15 + pdn) * APART +
                              ((kb0 + part) * 128 + row) * 16) = v;
  }
}

// fused: GU GEMM (1800 blocks) + DN weight repack (1800 blocks), 256 thr
__global__ __launch_bounds__(256, 3)
void gu_fused_k(const u8* __restrict__ xqT, const u8* __restrict__ wqgT,
                const float* __restrict__ gub,
                const int* __restrict__ tt_e, const int* __restrict__ tt_rows,
                u8* __restrict__ gqT,
                const int* __restrict__ dnc, const int* __restrict__ dns,
                u8* __restrict__ wqdT) {
  if (blockIdx.x < 1800)
    gu_gemm_body(blockIdx.x, xqT, wqgT, gub, tt_e, tt_rows, gqT);
  else
    repack_dn_body(blockIdx.x - 1800, threadIdx.x, dnc, dns, wqdT);
}

// ---------------- DN GEMM (r11 structure, byte-identical): BN=192, 6 waves ----
__global__ __launch_bounds__(384, 3)
void dn_k(const u8* __restrict__ gqT, const u8* __restrict__ wqdT,
          const float* __restrict__ dnb,
          const int* __restrict__ tt_e, const int* __restrict__ tt_rows,
          float* __restrict__ partial) {
  int lin = blockIdx.x;
  int xcd = lin & 7, pos = lin >> 3;
  int L = xcd * 75 + pos;              // 600 blocks
  int mt = L % 40, nt = L / 40;

  const int rows = tt_rows[mt];
  if (rows <= 0) return;
  const int e = tt_e[mt];
  const int tid = threadIdx.x;
  const int lane = tid & 63;
  const int wid = tid >> 6;
  const int wm = wid & 1;
  const int wn = wid >> 1;             // 3 n-waves, span 64
  const int ml = lane & 31;
  const int kc = lane >> 5;

  __shared__ __align__(16) u8 Tiles[2][36864];

  const u8* Abase = gqT + (long)mt * (15 * APART);
  const u8* Bbase = wqdT + (long)(e * 15 + nt) * (15 * BPART);

  const u8* csrc[6]; int cstep[6], cdst[6]; bool cval[6];
#pragma unroll
  for (int i = 0; i < 6; ++i) {
    int c = tid + i * 384;
    cval[i] = (c < 2080);
    if (c < 832)       { csrc[i] = Abase + c * 16;         cstep[i] = APART; }
    else if (c < 2080) { csrc[i] = Bbase + (c - 832) * 16; cstep[i] = BPART; }
    else               { csrc[i] = Abase;                  cstep[i] = 0; }
    cdst[i] = cval[i] ? c * 16 : 0;
  }
  auto stage = [&](int buf, int p) {
#pragma unroll
    for (int i = 0; i < 6; ++i)
      if (cval[i]) gll16(csrc[i] + (long)p * cstep[i], &Tiles[buf][cdst[i]]);
  };

  stage(0, 0);

  f32x16 acc[2][2];
#pragma unroll
  for (int a_ = 0; a_ < 2; ++a_)
#pragma unroll
    for (int b_ = 0; b_ < 2; ++b_)
#pragma unroll
      for (int k_ = 0; k_ < 16; ++k_) acc[a_][b_][k_] = 0.f;

  const int row0l = wm * 64 + ml;
  const int col0l = wn * 64 + ml;
  const bool act = (wm == 0) || (rows > 64);

  __syncthreads();

  for (int p = 0; p < 15; ++p) {
    const int cur = p & 1;
    if (p + 1 < 15) stage(cur ^ 1, p + 1);
    if (act) {
      const u8* T = Tiles[cur];
      u64 As0 = *reinterpret_cast<const u64*>(&T[12288 + row0l * 8]);
      u64 As1 = *reinterpret_cast<const u64*>(&T[12288 + (row0l + 32) * 8]);
      u64 Bs0 = *reinterpret_cast<const u64*>(&T[31744 + col0l * 8]);
      u64 Bs1 = *reinterpret_cast<const u64*>(&T[31744 + (col0l + 32) * 8]);
#pragma unroll
      for (int t = 0; t < 3; ++t) {
        const int kb = t * 2 + kc;
        const int sh = kb * 8;
        i32x4 af0 = *reinterpret_cast<const i32x4*>(&T[(kb * 128 + row0l) * 16]);
        i32x4 af1 = *reinterpret_cast<const i32x4*>(&T[(kb * 128 + row0l + 32) * 16]);
        i32x4 bf0 = *reinterpret_cast<const i32x4*>(&T[13312 + (kb * 192 + col0l) * 16]);
        i32x4 bf1 = *reinterpret_cast<const i32x4*>(&T[13312 + (kb * 192 + col0l + 32) * 16]);
        int sa0 = (int)((As0 >> sh) & 255), sa1 = (int)((As1 >> sh) & 255);
        int sb0 = (int)((Bs0 >> sh) & 255), sb1 = (int)((Bs1 >> sh) & 255);
        __builtin_amdgcn_s_setprio(1);
        acc[0][0] = __builtin_amdgcn_mfma_scale_f32_32x32x64_f8f6f4(
            ext8(af0), ext8(bf0), acc[0][0], 4, 4, 0, sa0, 0, sb0);
        acc[0][1] = __builtin_amdgcn_mfma_scale_f32_32x32x64_f8f6f4(
            ext8(af0), ext8(bf1), acc[0][1], 4, 4, 0, sa0, 0, sb1);
        acc[1][0] = __builtin_amdgcn_mfma_scale_f32_32x32x64_f8f6f4(
            ext8(af1), ext8(bf0), acc[1][0], 4, 4, 0, sa1, 0, sb0);
        acc[1][1] = __builtin_amdgcn_mfma_scale_f32_32x32x64_f8f6f4(
            ext8(af1), ext8(bf1), acc[1][1], 4, 4, 0, sa1, 0, sb1);
        __builtin_amdgcn_s_setprio(0);
      }
    }
    __syncthreads();
  }

  const int hlf = lane >> 5;
  const int row0 = mt * 128;
#pragma unroll
  for (int mf = 0; mf < 2; ++mf) {
#pragma unroll
    for (int rr = 0; rr < 16; ++rr) {
      int mrow = (rr & 3) + 8 * (rr >> 2) + 4 * hlf;
      int rloc = wm * 64 + mf * 32 + mrow;
      if (rloc >= rows) continue;
      long rg = row0 + rloc;
#pragma unroll
      for (int nf = 0; nf < 2; ++nf) {
        int hg = nt * 192 + wn * 64 + nf * 32 + ml;
        partial[rg * HD + hg] = acc[mf][nf][rr] + dnb[e * HD + hg];
      }
    }
  }
}

// ---------------- final combine: out[t] = sum_k rw[t,k] * partial[row(t,k)] ----
__global__ __launch_bounds__(768)
void gather_k(const float* __restrict__ partial, const int* __restrict__ tok2row,
              const float* __restrict__ rw, float* __restrict__ out) {
  int t = blockIdx.x;
  int i = threadIdx.x;
  if (i >= 720) return;            // 720*4 = 2880
  int c = i * 4;
  float4 s = make_float4(0.f, 0.f, 0.f, 0.f);
#pragma unroll
  for (int k = 0; k < 4; ++k) {
    int r = tok2row[t * 4 + k];
    float w = rw[t * 4 + k];
    float4 v = *reinterpret_cast<const float4*>(&partial[(long)r * HD + c]);
    s.x += w * v.x; s.y += w * v.y; s.z += w * v.z; s.w += w * v.w;
  }
  *reinterpret_cast<float4*>(&out[(long)t * HD + c]) = s;
}

// ---------------- launcher ----------------
extern "C" void kernel_launch(void* const* d_in, const int* in_sizes, int n_in,
                              void* d_out, int out_size, void* d_ws, size_t ws_size,
                              hipStream_t stream) {
  (void)in_sizes; (void)n_in; (void)ws_size; (void)out_size;
  const float* x   = (const float*)d_in[0];
  const int* ridx  = (const int*)d_in[1];
  const float* rw  = (const float*)d_in[2];
  const int* guc   = (const int*)d_in[3];
  const int* gus   = (const int*)d_in[4];
  const float* gub = (const float*)d_in[5];
  const int* dnc   = (const int*)d_in[6];
  const int* dns   = (const int*)d_in[7];
  const float* dnb = (const float*)d_in[8];
  float* out = (float*)d_out;
  char* ws = (char*)d_ws;

  // ws layout (~185 MB)
  int* tt_e    = (int*)(ws);
  int* tt_row0 = (int*)(ws + 1024);
  int* tt_rows = (int*)(ws + 2048);
  int* atok    = (int*)(ws + 4096);
  int* tok2row = (int*)(ws + 4096 + MAXPAD * 4);
  size_t off = 65536;
  u8* xqp = (u8*)(ws + off);  off += (size_t)NTOK * RB;                // 1.47 MB
  u8* xs  = (u8*)(ws + off);  off += (size_t)NTOK * XSB;               // 123 KB
  u8* xqT = (u8*)(ws + off);  off += (size_t)MAXTILES * 15 * APART;    // 7.99 MB
  u8* gqT = (u8*)(ws + off);  off += (size_t)MAXTILES * 15 * APART;    // 7.99 MB
  u8* wqgT = (u8*)(ws + off); off += (size_t)NEXP * 45 * 15 * BPGU;    // 71.9 MB
  u8* wqdT = (u8*)(ws + off); off += (size_t)NEXP * 15 * 15 * BPART;   // 35.9 MB
  float* partial = (float*)(ws + off); off += (size_t)MAXPAD * HD * 4; // 59 MB

  route_k<<<1, 256, 0, stream>>>(ridx, rw, tt_e, tt_row0, tt_rows, atok, tok2row);
  prep1_k<<<NTOK + 5400, 384, 0, stream>>>(x, xqp, xs, guc, gus, wqgT);
  gathx_k<<<MAXTILES, 384, 0, stream>>>(xqp, xs, atok, xqT);
  gu_fused_k<<<1800 + 1800, 256, 0, stream>>>(xqT, wqgT, gub, tt_e, tt_rows, gqT,
                                              dnc, dns, wqdT);
  dn_k<<<600, 384, 0, stream>>>(gqT, wqdT, dnb, tt_e, tt_rows, partial);
  gather_k<<<NTOK, 768, 0, stream>>>(partial, tok2row, rw, out);
}

// Round 16
// 379.550 us; speedup vs baseline: 1.3258x; 1.0117x over previous
//
#include <hip/hip_runtime.h>
#include <hip/hip_bf16.h>

typedef unsigned char u8;
typedef unsigned int u32;
typedef unsigned long long u64;
typedef int i32x4 __attribute__((ext_vector_type(4)));
typedef int i32x8 __attribute__((ext_vector_type(8)));
typedef float f32x16 __attribute__((ext_vector_type(16)));

#define HD 2880          // H == I == 2880
#define GUN 5760         // 2*I
#define NEXP 8
#define NTOK 1024
#define NASSIGN 4096     // T*K
#define MAXPAD 5120      // padded routed rows (40 tiles x 128)
#define MAXTILES 40
#define SROWS 90         // 2880/32
#define RB 1440          // packed fp4 row bytes (2880/2)
#define XSB 120          // activation scale row bytes: 15 phases x 8
// per-phase image pieces (BK = 192)
#define APART 13312      // A image: pay [kb(6)][row(128)][16B]=12288 + scl [row][8]=1024
#define BPGU 13312       // GU B image: pay [kb(6)][col(128)][16B]=12288 + scl [col][8]=1024
#define BPDN 6656        // DN B image: pay [kb(6)][col(64)][16B]=6144 + scl [col][8]=512

// ---------------- global -> LDS direct staging (16B per lane) ----------------
__device__ __forceinline__ void gll16(const void* g, void* l) {
  __builtin_amdgcn_global_load_lds(
      (const __attribute__((address_space(1))) u32*)g,
      (__attribute__((address_space(3))) u32*)l, 16, 0, 0);
}

// i32x4 -> i32x8 with UNDEF high half (fp4 MFMA reads only regs 0-3)
__device__ __forceinline__ i32x8 ext8(i32x4 v) {
  return __builtin_shufflevector(v, v, 0, 1, 2, 3, -1, -1, -1, -1);
}

// ---------------- exact mxfp4 code helper ----------------
__device__ __forceinline__ int quant_code(float v, float inv) {
  float x = v * inv;
  float a = fabsf(x);
  int n;
  if (x > 0.f)
    n = (a > 0.25f) + (a > 0.75f) + (a > 1.25f) + (a > 1.75f) +
        (a > 2.5f)  + (a > 3.5f)  + (a > 5.f);
  else
    n = (a >= 0.25f) + (a >= 0.75f) + (a >= 1.25f) + (a >= 1.75f) +
        (a >= 2.5f)  + (a >= 3.5f)  + (a >= 5.f);
  return x < 0.f ? (8 | n) : n;   // x==0 -> n==0 -> code 0
}

// ---------------- routing ----------------
__global__ __launch_bounds__(256)
void route_k(const int* __restrict__ ridx, const float* __restrict__ rw,
             int* __restrict__ tt_e, int* __restrict__ tt_row0, int* __restrict__ tt_rows,
             int* __restrict__ atok, int* __restrict__ tok2row) {
  __shared__ int cnt[NEXP], cur[NEXP], poff[NEXP];
  int tid = threadIdx.x;
  if (tid < NEXP) { cnt[tid] = 0; cur[tid] = 0; }
  __syncthreads();
  for (int a = tid; a < NASSIGN; a += 256) atomicAdd(&cnt[ridx[a]], 1);
  __syncthreads();
  if (tid == 0) {
    int off = 0, nt = 0;
    for (int e = 0; e < NEXP; ++e) {
      poff[e] = off;
      int cc = cnt[e];
      int ntl = (cc + 127) >> 7;
      for (int i = 0; i < ntl; ++i) {
        int rem = cc - i * 128;
        tt_e[nt] = e; tt_row0[nt] = off + i * 128; tt_rows[nt] = rem < 128 ? rem : 128;
        ++nt;
      }
      off += ntl * 128;
    }
    for (; nt < 64; ++nt) { tt_e[nt] = 0; tt_row0[nt] = 0; tt_rows[nt] = 0; }
  }
  __syncthreads();
  for (int r2 = tid; r2 < MAXPAD; r2 += 256) atok[r2] = 0;
  __syncthreads();
  for (int a = tid; a < NASSIGN; a += 256) {
    int e = ridx[a];
    int p = atomicAdd(&cur[e], 1);
    int r2 = poff[e] + p;
    atok[r2] = a >> 2;
    tok2row[a] = r2;
  }
}

// ---------------- activation quant ----------------
__device__ __forceinline__ void quant_x_body(int t, int tid, const float* __restrict__ x,
                                             u8* __restrict__ xqp, u8* __restrict__ xs) {
  if (tid >= 360) return;       // 360*8 = 2880
  const float* xp = x + (long)t * HD + tid * 8;
  float4 v0 = *reinterpret_cast<const float4*>(xp);
  float4 v1 = *reinterpret_cast<const float4*>(xp + 4);
  float vv[8] = {v0.x, v0.y, v0.z, v0.w, v1.x, v1.y, v1.z, v1.w};
  float am = 0.f;
#pragma unroll
  for (int j = 0; j < 8; ++j) am = fmaxf(am, fabsf(vv[j]));
  am = fmaxf(am, __shfl_xor(am, 1));
  am = fmaxf(am, __shfl_xor(am, 2));
  u32 eb = (__float_as_uint(am) >> 23) & 255u;
  float inv = __uint_as_float((256u - eb) << 23);
  u32 w = 0;
#pragma unroll
  for (int j = 0; j < 8; ++j) {
    u32 c = (am > 0.f) ? (u32)quant_code(vv[j], inv) : 0u;
    w |= c << (4 * j);          // low nibble = even k
  }
  *reinterpret_cast<u32*>(xqp + (long)t * RB + tid * 4) = w;
  if ((tid & 3) == 0) {
    int kb = tid >> 2;          // 0..89
    int p = kb / 6, j = kb % 6;
    xs[(long)t * XSB + p * 8 + j] = (u8)(am > 0.f ? (eb - 2u) : 0u);
  }
}

// ---------------- GU weight repack -> wqgT[(e*45+nt)][p][BPGU], 384 thr ----------
__device__ __forceinline__ void repack_gu_body(int idx, int tid,
                                               const int* __restrict__ codes,
                                               const int* __restrict__ scales,
                                               u8* __restrict__ wqgT) {
  const int ND = GUN;
  const int tile = idx / 15;       // e*45 + nt
  const int p = idx % 15;
  const int nt = tile % 45;
  const int e = tile / 45;
  u8* base = wqgT + ((long)tile * 15 + p) * BPGU;
  // payload: 768 chunks [kb(6)][col(128)]
#pragma unroll
  for (int i = 0; i < 2; ++i) {
    int c = tid + i * 384;
    int col = c & 127, kb = c >> 7;
    const int f = nt * 128 + col;
    const int* src = codes + ((long)e * HD + (p * 6 + kb) * 32) * ND + f;
    u32 w[4] = {0, 0, 0, 0};
#pragma unroll
    for (int j = 0; j < 32; ++j) {
      u32 cc = (u32)src[(long)j * ND] & 15u;
      w[j >> 3] |= cc << ((j & 7) * 4);
    }
    *reinterpret_cast<uint4*>(base + c * 16) = make_uint4(w[0], w[1], w[2], w[3]);
  }
  if (tid < 128) {
    const int f = nt * 128 + tid;
    u64 v = 0;
#pragma unroll
    for (int kb = 0; kb < 6; ++kb) {
      u32 s = (u32)(scales[((long)e * SROWS + p * 6 + kb) * ND + f] + 115) & 255u;
      v |= (u64)s << (kb * 8);
    }
    *reinterpret_cast<u64*>(base + 12288 + tid * 8) = v;
  }
}

// prep1: quant_x (1024 blocks) + GU repack (5400 blocks), 384 thr
__global__ __launch_bounds__(384)
void prep1_k(const float* __restrict__ x, u8* __restrict__ xqp, u8* __restrict__ xs,
             const int* __restrict__ guc, const int* __restrict__ gus,
             u8* __restrict__ wqgT) {
  const int b = blockIdx.x;
  const int tid = threadIdx.x;
  if (b < NTOK) quant_x_body(b, tid, x, xqp, xs);
  else repack_gu_body(b - NTOK, tid, guc, gus, wqgT);
}

// ---------------- DN weight repack -> wqdT[(e*45+nt)][p][BPDN], 256 thr ----------
__device__ __forceinline__ void repack_dn_body(int idx, int tid,
                                               const int* __restrict__ codes,
                                               const int* __restrict__ scales,
                                               u8* __restrict__ wqdT) {
  const int ND = HD;
  const int tile = idx / 15;       // e*45 + nt
  const int p = idx % 15;
  const int nt = tile % 45;
  const int e = tile / 45;
  u8* base = wqdT + ((long)tile * 15 + p) * BPDN;
  // payload: 384 chunks [kb(6)][col(64)]
#pragma unroll
  for (int i = 0; i < 2; ++i) {
    int c = tid + i * 256;
    if (c < 384) {
      int col = c & 63, kb = c >> 6;
      const int f = nt * 64 + col;
      const int* src = codes + ((long)e * HD + (p * 6 + kb) * 32) * ND + f;
      u32 w[4] = {0, 0, 0, 0};
#pragma unroll
      for (int j = 0; j < 32; ++j) {
        u32 cc = (u32)src[(long)j * ND] & 15u;
        w[j >> 3] |= cc << ((j & 7) * 4);
      }
      *reinterpret_cast<uint4*>(base + c * 16) = make_uint4(w[0], w[1], w[2], w[3]);
    }
  }
  if (tid < 64) {
    const int f = nt * 64 + tid;
    u64 v = 0;
#pragma unroll
    for (int kb = 0; kb < 6; ++kb) {
      u32 s = (u32)(scales[((long)e * SROWS + p * 6 + kb) * ND + f] + 115) & 255u;
      v |= (u64)s << (kb * 8);
    }
    *reinterpret_cast<u64*>(base + 6144 + tid * 8) = v;
  }
}

// ---------------- A gather: routed rows -> per-phase image xqT[mt][p][APART] ----
__global__ __launch_bounds__(384)
void gathx_k(const u8* __restrict__ xqp, const u8* __restrict__ xs,
             const int* __restrict__ atok, u8* __restrict__ xqT) {
  const int mt = blockIdx.x;
  const int tid = threadIdx.x;
  __shared__ int toks[128];
  if (tid < 128) toks[tid] = atok[mt * 128 + tid];
  __syncthreads();
  u8* base = xqT + (long)mt * (15 * APART);
#pragma unroll
  for (int i = 0; i < 30; ++i) {
    int idx = tid + i * 384;          // 11520 payload chunks
    int p = idx / 768, rem = idx % 768;
    uint4 v = *reinterpret_cast<const uint4*>(xqp + (long)toks[rem & 127] * RB +
                                              p * 96 + (rem >> 7) * 16);
    *reinterpret_cast<uint4*>(base + (long)p * APART + rem * 16) = v;
  }
#pragma unroll
  for (int i = 0; i < 5; ++i) {
    int idx = tid + i * 384;          // 1920 scale u64s
    int p = idx >> 7, row = idx & 127;
    u64 v = *reinterpret_cast<const u64*>(xs + (long)toks[row] * XSB + p * 8);
    *reinterpret_cast<u64*>(base + (long)p * APART + 12288 + row * 8) = v;
  }
}

// ---------------- GU GEMM body: BN=128, 4 waves (2m x 2n), 3 blocks/CU --------
// (byte-identical to verified round 15)
__device__ __forceinline__ void gu_gemm_body(
    int lin, const u8* __restrict__ xqT, const u8* __restrict__ wqgT,
    const float* __restrict__ gub,
    const int* __restrict__ tt_e, const int* __restrict__ tt_rows,
    u8* __restrict__ gqT) {
  int xcd = lin & 7, pos = lin >> 3;
  int L = xcd * 225 + pos;
  int mt = L % 40, nt = L / 40;        // nt 0..44

  const int rows = tt_rows[mt];
  if (rows <= 0) return;
  const int e = tt_e[mt];
  const int tid = threadIdx.x;         // 0..255
  const int lane = tid & 63;
  const int wid = tid >> 6;            // 0..3
  const int wm = wid & 1;              // 2 m-waves, span 64
  const int wn = wid >> 1;             // 2 n-waves, span 64
  const int ml = lane & 31;
  const int kc = lane >> 5;

  __shared__ __align__(16) u8 Tiles[2][26624];

  const u8* Abase = xqT + (long)mt * (15 * APART);
  const u8* Bbase = wqgT + (long)(e * 45 + nt) * (15 * BPGU);

  // 1664 chunks: threads 0..127 stage 7, rest 6
  const u8* csrc[7]; int cstep[7], cdst[7]; bool cval[7];
#pragma unroll
  for (int i = 0; i < 7; ++i) {
    int c = tid + i * 256;
    cval[i] = (c < 1664);
    if (c < 832)       { csrc[i] = Abase + c * 16;         cstep[i] = APART; cdst[i] = c * 16; }
    else if (c < 1664) { csrc[i] = Bbase + (c - 832) * 16; cstep[i] = BPGU;  cdst[i] = 13312 + (c - 832) * 16; }
    else               { csrc[i] = Abase; cstep[i] = 0; cdst[i] = 0; }
  }
  auto stage = [&](int buf, int p) {
#pragma unroll
    for (int i = 0; i < 7; ++i)
      if (cval[i]) gll16(csrc[i] + (long)p * cstep[i], &Tiles[buf][cdst[i]]);
  };

  stage(0, 0);

  f32x16 acc[2][2];
#pragma unroll
  for (int a_ = 0; a_ < 2; ++a_)
#pragma unroll
    for (int b_ = 0; b_ < 2; ++b_)
#pragma unroll
      for (int k_ = 0; k_ < 16; ++k_) acc[a_][b_][k_] = 0.f;

  const int row0l = wm * 64 + ml;
  const int col0l = wn * 64 + ml;
  const bool act = (wm == 0) || (rows > 64);

  __syncthreads();   // tile 0 staged

  for (int p = 0; p < 15; ++p) {
    const int cur = p & 1;
    if (p + 1 < 15) stage(cur ^ 1, p + 1);   // in flight under compute
    if (act) {
      const u8* T = Tiles[cur];
      u64 As0 = *reinterpret_cast<const u64*>(&T[12288 + row0l * 8]);
      u64 As1 = *reinterpret_cast<const u64*>(&T[12288 + (row0l + 32) * 8]);
      u64 Bs0 = *reinterpret_cast<const u64*>(&T[25600 + col0l * 8]);
      u64 Bs1 = *reinterpret_cast<const u64*>(&T[25600 + (col0l + 32) * 8]);
#pragma unroll
      for (int t = 0; t < 3; ++t) {
        const int kb = t * 2 + kc;
        const int sh = kb * 8;
        i32x4 af0 = *reinterpret_cast<const i32x4*>(&T[(kb * 128 + row0l) * 16]);
        i32x4 af1 = *reinterpret_cast<const i32x4*>(&T[(kb * 128 + row0l + 32) * 16]);
        i32x4 bf0 = *reinterpret_cast<const i32x4*>(&T[13312 + (kb * 128 + col0l) * 16]);
        i32x4 bf1 = *reinterpret_cast<const i32x4*>(&T[13312 + (kb * 128 + col0l + 32) * 16]);
        int sa0 = (int)((As0 >> sh) & 255), sa1 = (int)((As1 >> sh) & 255);
        int sb0 = (int)((Bs0 >> sh) & 255), sb1 = (int)((Bs1 >> sh) & 255);
        __builtin_amdgcn_s_setprio(1);
        acc[0][0] = __builtin_amdgcn_mfma_scale_f32_32x32x64_f8f6f4(
            ext8(af0), ext8(bf0), acc[0][0], 4, 4, 0, sa0, 0, sb0);
        acc[0][1] = __builtin_amdgcn_mfma_scale_f32_32x32x64_f8f6f4(
            ext8(af0), ext8(bf1), acc[0][1], 4, 4, 0, sa0, 0, sb1);
        acc[1][0] = __builtin_amdgcn_mfma_scale_f32_32x32x64_f8f6f4(
            ext8(af1), ext8(bf0), acc[1][0], 4, 4, 0, sa1, 0, sb0);
        acc[1][1] = __builtin_amdgcn_mfma_scale_f32_32x32x64_f8f6f4(
            ext8(af1), ext8(bf1), acc[1][1], 4, 4, 0, sa1, 0, sb1);
        __builtin_amdgcn_s_setprio(0);
      }
    }
    __syncthreads();
  }

  // ---- GU epilogue: 64 I-cols/block -> scale blocks {2nt, 2nt+1} ----
  const int hlf = lane >> 5;
  u8* Glds = &Tiles[0][0];             // 128 rows x 32 bytes
  const int pdn = nt / 3;              // 2nt/6
  const int kb0 = 2 * (nt % 3);        // even: never straddles a DN phase
  bool evenl = ((lane & 1) == 0);
#pragma unroll
  for (int mf = 0; mf < 2; ++mf) {
    float gated[2][16];
#pragma unroll
    for (int nf = 0; nf < 2; ++nf) {
      int fgc = nt * 128 + wn * 64 + nf * 32 + ml;
      float bown = gub[e * GUN + fgc];
#pragma unroll
      for (int rr = 0; rr < 16; ++rr) {
        float z = acc[mf][nf][rr] + bown;
        float zp = __shfl_xor(z, 1);
        float g = evenl ? z : zp;
        float u = evenl ? zp : z;
        g = fminf(g, 7.f);
        u = fminf(fmaxf(u, -7.f), 7.f);
        float sg = 1.f / (1.f + expf(-1.702f * g));
        gated[nf][rr] = (u + 1.f) * (g * sg);
      }
    }
#pragma unroll
    for (int rr = 0; rr < 16; ++rr) {
      float am = fmaxf(fabsf(gated[0][rr]), fabsf(gated[1][rr]));
      am = fmaxf(am, __shfl_xor(am, 2));
      am = fmaxf(am, __shfl_xor(am, 4));
      am = fmaxf(am, __shfl_xor(am, 8));
      am = fmaxf(am, __shfl_xor(am, 16));
      u32 eb = (__float_as_uint(am) >> 23) & 255u;
      float inv = __uint_as_float((256u - eb) << 23);
      int c0 = (am > 0.f) ? quant_code(gated[0][rr], inv) : 0;
      int c1 = (am > 0.f) ? quant_code(gated[1][rr], inv) : 0;
      int b0 = c0 | (__shfl_xor(c0, 2) << 4);   // valid at (lane&3)==0
      int b1 = c1 | (__shfl_xor(c1, 2) << 4);
      int mrow = (rr & 3) + 8 * (rr >> 2) + 4 * hlf;
      int rloc = wm * 64 + mf * 32 + mrow;
      if ((lane & 3) == 0) {
        Glds[rloc * 32 + wn * 16 + (ml >> 2)] = (u8)b0;
        Glds[rloc * 32 + wn * 16 + 8 + (ml >> 2)] = (u8)b1;
        if (rloc < rows && ml == 0)
          gqT[((long)mt * 15 + pdn) * APART + 12288 + rloc * 8 + kb0 + wn] =
              (u8)(am > 0.f ? (eb - 2u) : 0u);
      }
    }
  }
  __syncthreads();
  {
    int part = tid >> 7, row = tid & 127;     // 2 chunks x 128 rows
    uint4 v = *reinterpret_cast<const uint4*>(&Glds[row * 32 + part * 16]);
    *reinterpret_cast<uint4*>(gqT + ((long)mt * 15 + pdn) * APART +
                              ((kb0 + part) * 128 + row) * 16) = v;
  }
}

// fused: GU GEMM (1800 blocks) + DN weight repack (5400 blocks), 256 thr
__global__ __launch_bounds__(256, 3)
void gu_fused_k(const u8* __restrict__ xqT, const u8* __restrict__ wqgT,
                const float* __restrict__ gub,
                const int* __restrict__ tt_e, const int* __restrict__ tt_rows,
                u8* __restrict__ gqT,
                const int* __restrict__ dnc, const int* __restrict__ dns,
                u8* __restrict__ wqdT) {
  if (blockIdx.x < 1800)
    gu_gemm_body(blockIdx.x, xqT, wqgT, gub, tt_e, tt_rows, gqT);
  else
    repack_dn_body(blockIdx.x - 1800, threadIdx.x, dnc, dns, wqdT);
}

// ---------------- DN GEMM: BN=64, 2 waves (2m x 1n), 4 blocks/CU --------------
// BM=128, BK=192 -> 15 phases, 12 MFMA/thread/phase (same inner mix as GU).
// LDS 2 x 19968 = 39.9 KB -> 4 desynced blocks/CU. 1800 blocks (40mt x 45nt).
__global__ __launch_bounds__(128, 2)
void dn_k(const u8* __restrict__ gqT, const u8* __restrict__ wqdT,
          const float* __restrict__ dnb,
          const int* __restrict__ tt_e, const int* __restrict__ tt_rows,
          float* __restrict__ partial) {
  int lin = blockIdx.x;
  int xcd = lin & 7, pos = lin >> 3;
  int L = xcd * 225 + pos;             // 1800 blocks
  int mt = L % 40, nt = L / 40;        // nt 0..44

  const int rows = tt_rows[mt];
  if (rows <= 0) return;
  const int e = tt_e[mt];
  const int tid = threadIdx.x;         // 0..127
  const int lane = tid & 63;
  const int wid = tid >> 6;            // 0..1
  const int wm = wid;                  // 2 m-waves, span 64
  const int ml = lane & 31;
  const int kc = lane >> 5;

  __shared__ __align__(16) u8 Tiles[2][19968];

  const u8* Abase = gqT + (long)mt * (15 * APART);
  const u8* Bbase = wqdT + (long)(e * 45 + nt) * (15 * BPDN);

  // 1248 chunks: slots 0..8 full (tid+i*128), slot 9 tid<96
  const u8* csrc[10]; int cstep[10], cdst[10]; bool cval[10];
#pragma unroll
  for (int i = 0; i < 10; ++i) {
    int c = tid + i * 128;
    cval[i] = (c < 1248);
    if (c < 832)       { csrc[i] = Abase + c * 16;         cstep[i] = APART; cdst[i] = c * 16; }
    else if (c < 1248) { csrc[i] = Bbase + (c - 832) * 16; cstep[i] = BPDN;  cdst[i] = 13312 + (c - 832) * 16; }
    else               { csrc[i] = Abase; cstep[i] = 0; cdst[i] = 0; }
  }
  auto stage = [&](int buf, int p) {
#pragma unroll
    for (int i = 0; i < 10; ++i)
      if (cval[i]) gll16(csrc[i] + (long)p * cstep[i], &Tiles[buf][cdst[i]]);
  };

  stage(0, 0);

  f32x16 acc[2][2];
#pragma unroll
  for (int a_ = 0; a_ < 2; ++a_)
#pragma unroll
    for (int b_ = 0; b_ < 2; ++b_)
#pragma unroll
      for (int k_ = 0; k_ < 16; ++k_) acc[a_][b_][k_] = 0.f;

  const int row0l = wm * 64 + ml;
  const int col0l = ml;                // single n-wave, span 64
  const bool act = (wm == 0) || (rows > 64);

  __syncthreads();   // tile 0 staged

  for (int p = 0; p < 15; ++p) {
    const int cur = p & 1;
    if (p + 1 < 15) stage(cur ^ 1, p + 1);   // in flight under compute
    if (act) {
      const u8* T = Tiles[cur];
      u64 As0 = *reinterpret_cast<const u64*>(&T[12288 + row0l * 8]);
      u64 As1 = *reinterpret_cast<const u64*>(&T[12288 + (row0l + 32) * 8]);
      u64 Bs0 = *reinterpret_cast<const u64*>(&T[19456 + col0l * 8]);
      u64 Bs1 = *reinterpret_cast<const u64*>(&T[19456 + (col0l + 32) * 8]);
#pragma unroll
      for (int t = 0; t < 3; ++t) {
        const int kb = t * 2 + kc;
        const int sh = kb * 8;
        i32x4 af0 = *reinterpret_cast<const i32x4*>(&T[(kb * 128 + row0l) * 16]);
        i32x4 af1 = *reinterpret_cast<const i32x4*>(&T[(kb * 128 + row0l + 32) * 16]);
        i32x4 bf0 = *reinterpret_cast<const i32x4*>(&T[13312 + (kb * 64 + col0l) * 16]);
        i32x4 bf1 = *reinterpret_cast<const i32x4*>(&T[13312 + (kb * 64 + col0l + 32) * 16]);
        int sa0 = (int)((As0 >> sh) & 255), sa1 = (int)((As1 >> sh) & 255);
        int sb0 = (int)((Bs0 >> sh) & 255), sb1 = (int)((Bs1 >> sh) & 255);
        __builtin_amdgcn_s_setprio(1);
        acc[0][0] = __builtin_amdgcn_mfma_scale_f32_32x32x64_f8f6f4(
            ext8(af0), ext8(bf0), acc[0][0], 4, 4, 0, sa0, 0, sb0);
        acc[0][1] = __builtin_amdgcn_mfma_scale_f32_32x32x64_f8f6f4(
            ext8(af0), ext8(bf1), acc[0][1], 4, 4, 0, sa0, 0, sb1);
        acc[1][0] = __builtin_amdgcn_mfma_scale_f32_32x32x64_f8f6f4(
            ext8(af1), ext8(bf0), acc[1][0], 4, 4, 0, sa1, 0, sb0);
        acc[1][1] = __builtin_amdgcn_mfma_scale_f32_32x32x64_f8f6f4(
            ext8(af1), ext8(bf1), acc[1][1], 4, 4, 0, sa1, 0, sb1);
        __builtin_amdgcn_s_setprio(0);
      }
    }
    __syncthreads();
  }

  const int hlf = lane >> 5;
  const int row0 = mt * 128;
#pragma unroll
  for (int mf = 0; mf < 2; ++mf) {
#pragma unroll
    for (int rr = 0; rr < 16; ++rr) {
      int mrow = (rr & 3) + 8 * (rr >> 2) + 4 * hlf;
      int rloc = wm * 64 + mf * 32 + mrow;
      if (rloc >= rows) continue;
      long rg = row0 + rloc;
#pragma unroll
      for (int nf = 0; nf < 2; ++nf) {
        int hg = nt * 64 + nf * 32 + ml;
        partial[rg * HD + hg] = acc[mf][nf][rr] + dnb[e * HD + hg];
      }
    }
  }
}

// ---------------- final combine: out[t] = sum_k rw[t,k] * partial[row(t,k)] ----
__global__ __launch_bounds__(768)
void gather_k(const float* __restrict__ partial, const int* __restrict__ tok2row,
              const float* __restrict__ rw, float* __restrict__ out) {
  int t = blockIdx.x;
  int i = threadIdx.x;
  if (i >= 720) return;            // 720*4 = 2880
  int c = i * 4;
  float4 s = make_float4(0.f, 0.f, 0.f, 0.f);
#pragma unroll
  for (int k = 0; k < 4; ++k) {
    int r = tok2row[t * 4 + k];
    float w = rw[t * 4 + k];
    float4 v = *reinterpret_cast<const float4*>(&partial[(long)r * HD + c]);
    s.x += w * v.x; s.y += w * v.y; s.z += w * v.z; s.w += w * v.w;
  }
  *reinterpret_cast<float4*>(&out[(long)t * HD + c]) = s;
}

// ---------------- launcher ----------------
extern "C" void kernel_launch(void* const* d_in, const int* in_sizes, int n_in,
                              void* d_out, int out_size, void* d_ws, size_t ws_size,
                              hipStream_t stream) {
  (void)in_sizes; (void)n_in; (void)ws_size; (void)out_size;
  const float* x   = (const float*)d_in[0];
  const int* ridx  = (const int*)d_in[1];
  const float* rw  = (const float*)d_in[2];
  const int* guc   = (const int*)d_in[3];
  const int* gus   = (const int*)d_in[4];
  const float* gub = (const float*)d_in[5];
  const int* dnc   = (const int*)d_in[6];
  const int* dns   = (const int*)d_in[7];
  const float* dnb = (const float*)d_in[8];
  float* out = (float*)d_out;
  char* ws = (char*)d_ws;

  // ws layout (~185 MB)
  int* tt_e    = (int*)(ws);
  int* tt_row0 = (int*)(ws + 1024);
  int* tt_rows = (int*)(ws + 2048);
  int* atok    = (int*)(ws + 4096);
  int* tok2row = (int*)(ws + 4096 + MAXPAD * 4);
  size_t off = 65536;
  u8* xqp = (u8*)(ws + off);  off += (size_t)NTOK * RB;                // 1.47 MB
  u8* xs  = (u8*)(ws + off);  off += (size_t)NTOK * XSB;               // 123 KB
  u8* xqT = (u8*)(ws + off);  off += (size_t)MAXTILES * 15 * APART;    // 7.99 MB
  u8* gqT = (u8*)(ws + off);  off += (size_t)MAXTILES * 15 * APART;    // 7.99 MB
  u8* wqgT = (u8*)(ws + off); off += (size_t)NEXP * 45 * 15 * BPGU;    // 71.9 MB
  u8* wqdT = (u8*)(ws + off); off += (size_t)NEXP * 45 * 15 * BPDN;    // 35.9 MB
  float* partial = (float*)(ws + off); off += (size_t)MAXPAD * HD * 4; // 59 MB

  route_k<<<1, 256, 0, stream>>>(ridx, rw, tt_e, tt_row0, tt_rows, atok, tok2row);
  prep1_k<<<NTOK + 5400, 384, 0, stream>>>(x, xqp, xs, guc, gus, wqgT);
  gathx_k<<<MAXTILES, 384, 0, stream>>>(xqp, xs, atok, xqT);
  gu_fused_k<<<1800 + 5400, 256, 0, stream>>>(xqT, wqgT, gub, tt_e, tt_rows, gqT,
                                              dnc, dns, wqdT);
  dn_k<<<1800, 128, 0, stream>>>(gqT, wqdT, dnb, tt_e, tt_rows, partial);
  gather_k<<<NTOK, 768, 0, stream>>>(partial, tok2row, rw, out);
}